// Round 7
// baseline (434.092 us; speedup 1.0000x reference)
//
#include <hip/hip_runtime.h>
#include <hip/hip_bf16.h>
#include <math.h>

// GAT 2-layer. Round 7: per-edge softmax weights precomputed in CSR order
// (kscat computes wcsr[4] per edge; mega2's kw2 role computes w2csr), so the
// gather kernels are pure weighted-sum loops. Launch fusion: ksetup
// (W1 swizzle | W2 prep | deg zero), mega1 (kh1 MFMA GEMM | khist),
// kscan1, kscan2, kscat, kg1, mega2 (kh2 | kw2), kg2. kscan3 folded into
// consumers via bsum[d>>10].

typedef unsigned short u16;
typedef unsigned int u32;
typedef __attribute__((ext_vector_type(8))) short bf16x8;
typedef __attribute__((ext_vector_type(4))) float f32x4;

__device__ __forceinline__ float eluf(float v) { return v > 0.f ? v : expm1f(v); }
__device__ __forceinline__ u16 f2bf(float f) {
    u32 u = __float_as_uint(f);
    u += 0x7fff + ((u >> 16) & 1);          // RNE
    return (u16)(u >> 16);
}
__device__ __forceinline__ float bf2f(u16 u) {
    return __uint_as_float(((u32)u) << 16);
}
// exp(leaky02(e)) = exp2(e * (e>=0 ? log2e : 0.2*log2e))
__device__ __forceinline__ float expleaky(float e) {
    float m = e >= 0.f ? 1.44269504f : 0.28853901f;
    return exp2f(e * m);
}

// ---------------- ksetup: W1 frag swizzle | W2 prep | deg zero -------------
__global__ __launch_bounds__(256) void ksetup(
    const float* __restrict__ W1, const float* __restrict__ W2,
    const float* __restrict__ ats2, const float* __restrict__ atd2,
    u16* __restrict__ w1fh, u16* __restrict__ w1fl,
    float* __restrict__ u, float* __restrict__ v, u16* __restrict__ w2tb,
    int* __restrict__ deg, int N)
{
    const int b = blockIdx.x, tid = threadIdx.x;
    if (b < 64) {
        // frag idx -> W1[k=q*32+(l>>4)*8+j][n=ct*16+(l&15)], hi/lo bf16
        int idx = b * 256 + tid;
        int j = idx & 7, l = (idx >> 3) & 63, q = (idx >> 9) & 3, ct = idx >> 11;
        int k = q * 32 + (l >> 4) * 8 + j;
        int n = ct * 16 + (l & 15);
        float w = W1[k * 128 + n];
        u16 hv = f2bf(w);
        w1fh[idx] = hv;
        w1fl[idx] = f2bf(w - bf2f(hv));
    } else if (b == 64) {
        if (tid < 128) {
            float su = 0.f, sv = 0.f;
            #pragma unroll
            for (int j = 0; j < 16; ++j) {
                float w = W2[tid * 16 + j];
                su = fmaf(w, ats2[j], su);
                sv = fmaf(w, atd2[j], sv);
                w2tb[j * 128 + tid] = f2bf(w);
            }
            u[tid] = su; v[tid] = sv;
        }
    } else {
        int z = (b - 65) * 1024 + tid * 4;
        if (z < N) *(int4*)&deg[z] = make_int4(0, 0, 0, 0);
    }
}

// ---------------- mega1: kh1 (MFMA hi/lo GEMM) | khist ---------------------
__global__ __launch_bounds__(256) void mega1(
    const float* __restrict__ x, const u16* __restrict__ w1fh,
    const u16* __restrict__ w1fl,
    const float* __restrict__ att_s, const float* __restrict__ att_d,
    u16* __restrict__ h1b, float* __restrict__ as1, float* __restrict__ ad1,
    int N,
    const int* __restrict__ ei, int* __restrict__ deg, int* __restrict__ rank,
    int E, int Bh1)
{
    __shared__ u16 lh[8192];
    __shared__ u16 ll[8192];
    if (blockIdx.x >= Bh1) {               // khist role
        int e = (blockIdx.x - Bh1) * 256 + threadIdx.x;
        if (e < E) rank[e] = atomicAdd(&deg[ei[E + e]], 1);
        return;
    }
    // kh1 role: 4 waves x 16 rows; two passes over ct (32 KB LDS)
    const int tid = threadIdx.x;
    const int wv = tid >> 6, lane = tid & 63;
    const int base = blockIdx.x * 64 + wv * 16;
    const int m = lane & 15, quad = lane >> 4;

    int arow = base + m;
    if (arow >= N) arow = 0;
    const float* xr = &x[(size_t)arow * 128 + quad * 8];
    bf16x8 ah[4], al[4];
    #pragma unroll
    for (int q = 0; q < 4; ++q) {
        float4 f0 = *(const float4*)&xr[q * 32];
        float4 f1 = *(const float4*)&xr[q * 32 + 4];
        float fv[8] = {f0.x, f0.y, f0.z, f0.w, f1.x, f1.y, f1.z, f1.w};
        union { u16 us[8]; bf16x8 v; } hh, lu;
        #pragma unroll
        for (int j = 0; j < 8; ++j) {
            u16 h = f2bf(fv[j]);
            hh.us[j] = h;
            lu.us[j] = f2bf(fv[j] - bf2f(h));
        }
        ah[q] = hh.v; al[q] = lu.v;
    }

    for (int p = 0; p < 2; ++p) {
        __syncthreads();
        #pragma unroll
        for (int i = 0; i < 4; ++i) {
            int fi = (tid + i * 256) * 8;
            *(uint4*)&lh[fi] = *(const uint4*)&w1fh[p * 8192 + fi];
            *(uint4*)&ll[fi] = *(const uint4*)&w1fl[p * 8192 + fi];
        }
        __syncthreads();
        #pragma unroll
        for (int hh2 = 0; hh2 < 2; ++hh2) {
            const int h = p * 2 + hh2;
            float sp[4] = {0.f, 0.f, 0.f, 0.f};
            float dp[4] = {0.f, 0.f, 0.f, 0.f};
            #pragma unroll
            for (int sub = 0; sub < 2; ++sub) {
                const int ctl = hh2 * 2 + sub;   // local ct within pass
                const int ct = p * 4 + ctl;      // global ct
                f32x4 acc = {0.f, 0.f, 0.f, 0.f};
                #pragma unroll
                for (int q = 0; q < 4; ++q) {
                    const int off = ((ctl * 4 + q) * 64 + lane) * 8;
                    bf16x8 bh = *(const bf16x8*)&lh[off];
                    bf16x8 bl = *(const bf16x8*)&ll[off];
                    acc = __builtin_amdgcn_mfma_f32_16x16x32_bf16(ah[q], bh, acc, 0, 0, 0);
                    acc = __builtin_amdgcn_mfma_f32_16x16x32_bf16(al[q], bh, acc, 0, 0, 0);
                    acc = __builtin_amdgcn_mfma_f32_16x16x32_bf16(ah[q], bl, acc, 0, 0, 0);
                }
                const float cs = att_s[h * 32 + sub * 16 + m];
                const float cd = att_d[h * 32 + sub * 16 + m];
                #pragma unroll
                for (int r = 0; r < 4; ++r) {
                    int rr = base + quad * 4 + r;
                    if (rr < N) h1b[(size_t)rr * 128 + ct * 16 + m] = f2bf(acc[r]);
                    sp[r] = fmaf(acc[r], cs, sp[r]);
                    dp[r] = fmaf(acc[r], cd, dp[r]);
                }
            }
            #pragma unroll
            for (int r = 0; r < 4; ++r) {
                sp[r] += __shfl_xor(sp[r], 1); sp[r] += __shfl_xor(sp[r], 2);
                sp[r] += __shfl_xor(sp[r], 4); sp[r] += __shfl_xor(sp[r], 8);
                dp[r] += __shfl_xor(dp[r], 1); dp[r] += __shfl_xor(dp[r], 2);
                dp[r] += __shfl_xor(dp[r], 4); dp[r] += __shfl_xor(dp[r], 8);
            }
            if (m == 0) {
                #pragma unroll
                for (int r = 0; r < 4; ++r) {
                    int rr = base + quad * 4 + r;
                    if (rr < N) {
                        as1[rr * 4 + h] = sp[r];
                        ad1[rr * 4 + h] = dp[r];
                    }
                }
            }
        }
    }
}

// ---------------- kscan1 / kscan2 ------------------------------------------
__global__ __launch_bounds__(256) void kscan1(
    const int* __restrict__ deg, int* __restrict__ rowptr,
    int* __restrict__ bsum, int N)
{
    __shared__ int lds[256];
    const int t = threadIdx.x;
    const int base = blockIdx.x * 1024 + t * 4;
    int v[4];
    int s = 0;
    #pragma unroll
    for (int j = 0; j < 4; ++j) {
        v[j] = (base + j < N) ? deg[base + j] : 0;
        s += v[j];
    }
    lds[t] = s;
    __syncthreads();
    for (int off = 1; off < 256; off <<= 1) {
        int y = (t >= off) ? lds[t - off] : 0;
        __syncthreads();
        lds[t] += y;
        __syncthreads();
    }
    int run = lds[t] - s;
    #pragma unroll
    for (int j = 0; j < 4; ++j) {
        if (base + j < N) rowptr[base + j] = run;
        run += v[j];
    }
    if (t == 255) bsum[blockIdx.x] = lds[255];
}

__global__ __launch_bounds__(128) void kscan2(int* __restrict__ bsum, int NB)
{
    __shared__ int lds[128];
    const int t = threadIdx.x;
    int v = (t < NB) ? bsum[t] : 0;
    lds[t] = v;
    __syncthreads();
    for (int off = 1; off < 128; off <<= 1) {
        int y = (t >= off) ? lds[t - off] : 0;
        __syncthreads();
        lds[t] += y;
        __syncthreads();
    }
    if (t < NB) bsum[t] = lds[t] - v;
}

// ---------------- kscat: scatter + per-edge layer-1 weights ----------------
__global__ __launch_bounds__(256) void kscat(
    const int* __restrict__ ei, const int* __restrict__ rowptr,
    const int* __restrict__ bsum, const int* __restrict__ rank,
    const float* __restrict__ as1, const float* __restrict__ ad1,
    int* __restrict__ colidx, int* __restrict__ dstid,
    float* __restrict__ wcsr, int E)
{
    int e = blockIdx.x * 256 + threadIdx.x;
    if (e >= E) return;
    int s = ei[e], d = ei[E + e];
    int pos = rowptr[d] + bsum[d >> 10] + rank[e];
    colidx[pos] = s;
    dstid[pos] = d;
    float4 av = *(const float4*)&as1[s * 4];
    float4 dv = *(const float4*)&ad1[d * 4];
    float4 w;
    w.x = expleaky(av.x + dv.x);
    w.y = expleaky(av.y + dv.y);
    w.z = expleaky(av.z + dv.z);
    w.w = expleaky(av.w + dv.w);
    *(float4*)&wcsr[(size_t)pos * 4] = w;
}

// ---------------- KG1: layer-1 weighted gather + elu -> x2(bf16)+as2/ad2 ---
__global__ __launch_bounds__(256) void kg1(
    const int* __restrict__ rowptr, const int* __restrict__ bsum,
    const int* __restrict__ colidx, const float* __restrict__ wcsr,
    const u16* __restrict__ h1b, const float* __restrict__ as1,
    const float* __restrict__ ad1, const float* __restrict__ b1,
    const float* __restrict__ u, const float* __restrict__ v,
    u16* __restrict__ x2b, float* __restrict__ as2, float* __restrict__ ad2,
    int N, int E)
{
    const int d = blockIdx.x * 4 + (threadIdx.x >> 6);
    if (d >= N) return;
    const int lane = threadIdx.x & 63;
    const int c = lane * 2;
    const int head = lane >> 4;

    const float ad_d = ad1[d * 4 + head];
    const float as_d = as1[d * 4 + head];
    const float wself = expleaky(as_d + ad_d);
    u32 hd = *(const u32*)&h1b[(d << 7) + c];
    float accx = wself * bf2f((u16)hd);
    float accy = wself * bf2f((u16)(hd >> 16));
    float den = wself;

    int i0 = rowptr[d] + bsum[d >> 10];
    int i1 = (d + 1 == N) ? E : rowptr[d + 1] + bsum[(d + 1) >> 10];
    i0 = __builtin_amdgcn_readfirstlane(i0);
    i1 = __builtin_amdgcn_readfirstlane(i1);
    int i = i0;
    for (; i + 8 <= i1; i += 8) {
        int s0 = colidx[i + 0];
        int s1 = colidx[i + 1];
        int s2 = colidx[i + 2];
        int s3 = colidx[i + 3];
        int s4 = colidx[i + 4];
        int s5 = colidx[i + 5];
        int s6 = colidx[i + 6];
        int s7 = colidx[i + 7];
        float w0 = wcsr[((i + 0) << 2) + head];
        float w1 = wcsr[((i + 1) << 2) + head];
        float w2 = wcsr[((i + 2) << 2) + head];
        float w3 = wcsr[((i + 3) << 2) + head];
        float w4 = wcsr[((i + 4) << 2) + head];
        float w5 = wcsr[((i + 5) << 2) + head];
        float w6 = wcsr[((i + 6) << 2) + head];
        float w7 = wcsr[((i + 7) << 2) + head];
        u32 v0 = *(const u32*)&h1b[(s0 << 7) + c];
        u32 v1 = *(const u32*)&h1b[(s1 << 7) + c];
        u32 v2 = *(const u32*)&h1b[(s2 << 7) + c];
        u32 v3 = *(const u32*)&h1b[(s3 << 7) + c];
        u32 v4 = *(const u32*)&h1b[(s4 << 7) + c];
        u32 v5 = *(const u32*)&h1b[(s5 << 7) + c];
        u32 v6 = *(const u32*)&h1b[(s6 << 7) + c];
        u32 v7 = *(const u32*)&h1b[(s7 << 7) + c];
        accx = fmaf(w0, bf2f((u16)v0), accx); accy = fmaf(w0, bf2f((u16)(v0 >> 16)), accy);
        accx = fmaf(w1, bf2f((u16)v1), accx); accy = fmaf(w1, bf2f((u16)(v1 >> 16)), accy);
        accx = fmaf(w2, bf2f((u16)v2), accx); accy = fmaf(w2, bf2f((u16)(v2 >> 16)), accy);
        accx = fmaf(w3, bf2f((u16)v3), accx); accy = fmaf(w3, bf2f((u16)(v3 >> 16)), accy);
        accx = fmaf(w4, bf2f((u16)v4), accx); accy = fmaf(w4, bf2f((u16)(v4 >> 16)), accy);
        accx = fmaf(w5, bf2f((u16)v5), accx); accy = fmaf(w5, bf2f((u16)(v5 >> 16)), accy);
        accx = fmaf(w6, bf2f((u16)v6), accx); accy = fmaf(w6, bf2f((u16)(v6 >> 16)), accy);
        accx = fmaf(w7, bf2f((u16)v7), accx); accy = fmaf(w7, bf2f((u16)(v7 >> 16)), accy);
        den += ((w0 + w1) + (w2 + w3)) + ((w4 + w5) + (w6 + w7));
    }
    for (; i < i1; ++i) {
        int s = colidx[i];
        float w = wcsr[(i << 2) + head];
        u32 hv = *(const u32*)&h1b[(s << 7) + c];
        accx = fmaf(w, bf2f((u16)hv), accx);
        accy = fmaf(w, bf2f((u16)(hv >> 16)), accy);
        den += w;
    }

    const float inv = 1.f / den;
    const float2 bv = *(const float2*)&b1[c];
    const float x2a = eluf(fmaf(accx, inv, bv.x));
    const float x2c = eluf(fmaf(accy, inv, bv.y));

    u32 pk = ((u32)f2bf(x2c) << 16) | (u32)f2bf(x2a);
    *(u32*)&x2b[(d << 7) + c] = pk;

    const float2 uv = *(const float2*)&u[c];
    const float2 vv = *(const float2*)&v[c];
    float sA = fmaf(x2a, uv.x, x2c * uv.y);
    float sB = fmaf(x2a, vv.x, x2c * vv.y);
    #pragma unroll
    for (int m = 1; m < 64; m <<= 1) {
        sA += __shfl_xor(sA, m);
        sB += __shfl_xor(sB, m);
    }
    if (lane == 0) { as2[d] = sA; ad2[d] = sB; }
}

// ---------------- mega2: kh2 (MFMA h2=x2@W2) | kw2 (layer-2 weights) -------
__global__ __launch_bounds__(256) void mega2(
    const u16* __restrict__ x2b, const u16* __restrict__ w2tb,
    u16* __restrict__ h2b, int N,
    const int* __restrict__ colidx, const int* __restrict__ dstid,
    const float* __restrict__ as2, const float* __restrict__ ad2,
    float* __restrict__ w2csr, int E, int Bh2)
{
    if (blockIdx.x >= Bh2) {               // kw2 role
        int i = (blockIdx.x - Bh2) * 256 + threadIdx.x;
        if (i < E) {
            int s = colidx[i], dd = dstid[i];
            w2csr[i] = expleaky(as2[s] + ad2[dd]);
        }
        return;
    }
    const int wv = threadIdx.x >> 6, lane = threadIdx.x & 63;
    const int n0 = blockIdx.x * 64 + wv * 16;
    if (n0 >= N) return;
    const int m = lane & 15;
    const int kq = lane >> 4;
    bf16x8 bfr[4];
    #pragma unroll
    for (int q = 0; q < 4; ++q)
        bfr[q] = *(const bf16x8*)&w2tb[m * 128 + q * 32 + kq * 8];

    int ar = n0 + m;
    if (ar >= N) ar = N - 1;
    const u16* arow = &x2b[((size_t)ar << 7) + kq * 8];
    f32x4 acc = {0.f, 0.f, 0.f, 0.f};
    #pragma unroll
    for (int q = 0; q < 4; ++q) {
        bf16x8 af = *(const bf16x8*)&arow[q * 32];
        acc = __builtin_amdgcn_mfma_f32_16x16x32_bf16(af, bfr[q], acc, 0, 0, 0);
    }
    #pragma unroll
    for (int r = 0; r < 4; ++r) {
        int rr = n0 + kq * 4 + r;
        if (rr < N) h2b[((size_t)rr << 4) + m] = f2bf(acc[r]);
    }
}

// ---------------- KG2: layer-2 weighted gather -> out ----------------------
__global__ __launch_bounds__(256) void kg2(
    const int* __restrict__ rowptr, const int* __restrict__ bsum,
    const int* __restrict__ colidx, const float* __restrict__ w2csr,
    const u16* __restrict__ h2b, const float* __restrict__ as2,
    const float* __restrict__ ad2, const float* __restrict__ b2,
    float* __restrict__ out, int N, int E)
{
    const int d = blockIdx.x * 4 + (threadIdx.x >> 6);
    if (d >= N) return;
    const int lane = threadIdx.x & 63;
    const int ch = lane & 7, g = lane >> 3;   // channels 2ch,2ch+1

    float acc0 = 0.f, acc1 = 0.f, den = 0.f;
    int i0 = rowptr[d] + bsum[d >> 10];
    int i1 = (d + 1 == N) ? E : rowptr[d + 1] + bsum[(d + 1) >> 10];
    i0 = __builtin_amdgcn_readfirstlane(i0);
    i1 = __builtin_amdgcn_readfirstlane(i1);
    int i = i0 + g;
    for (; i + 8 < i1; i += 16) {
        int s0 = colidx[i];
        int s1 = colidx[i + 8];
        float w0 = w2csr[i];
        float w1 = w2csr[i + 8];
        u32 v0 = *(const u32*)&h2b[(s0 << 4) + ch * 2];
        u32 v1 = *(const u32*)&h2b[(s1 << 4) + ch * 2];
        acc0 = fmaf(w0, bf2f((u16)v0), acc0);
        acc1 = fmaf(w0, bf2f((u16)(v0 >> 16)), acc1);
        acc0 = fmaf(w1, bf2f((u16)v1), acc0);
        acc1 = fmaf(w1, bf2f((u16)(v1 >> 16)), acc1);
        den += w0 + w1;
    }
    for (; i < i1; i += 8) {
        int s = colidx[i];
        float w = w2csr[i];
        u32 hv = *(const u32*)&h2b[(s << 4) + ch * 2];
        acc0 = fmaf(w, bf2f((u16)hv), acc0);
        acc1 = fmaf(w, bf2f((u16)(hv >> 16)), acc1);
        den += w;
    }
    acc0 += __shfl_xor(acc0, 8); acc0 += __shfl_xor(acc0, 16); acc0 += __shfl_xor(acc0, 32);
    acc1 += __shfl_xor(acc1, 8); acc1 += __shfl_xor(acc1, 16); acc1 += __shfl_xor(acc1, 32);
    den  += __shfl_xor(den, 8);  den  += __shfl_xor(den, 16);  den  += __shfl_xor(den, 32);

    const float wself = expleaky(as2[d] + ad2[d]);
    u32 hd = *(const u32*)&h2b[(d << 4) + ch * 2];
    acc0 = fmaf(wself, bf2f((u16)hd), acc0);
    acc1 = fmaf(wself, bf2f((u16)(hd >> 16)), acc1);
    den += wself;
    if (g == 0) {
        float2 ov = {acc0 / den + b2[ch * 2], acc1 / den + b2[ch * 2 + 1]};
        *(float2*)&out[(d << 4) + ch * 2] = ov;
    }
}

extern "C" void kernel_launch(void* const* d_in, const int* in_sizes, int n_in,
                              void* d_out, int out_size, void* d_ws, size_t ws_size,
                              hipStream_t stream) {
    const float* x    = (const float*)d_in[0];
    const int*   ei   = (const int*)d_in[1];
    const float* W1   = (const float*)d_in[2];
    const float* ats1 = (const float*)d_in[3];
    const float* atd1 = (const float*)d_in[4];
    const float* b1   = (const float*)d_in[5];
    const float* W2   = (const float*)d_in[6];
    const float* ats2 = (const float*)d_in[7];
    const float* atd2 = (const float*)d_in[8];
    const float* b2   = (const float*)d_in[9];
    float* out = (float*)d_out;
    const int N = in_sizes[0] / 128;
    const int E = in_sizes[1] / 2;

    u16* h1b   = (u16*)d_ws;                        // 128N
    u16* x2b   = h1b + (size_t)N * 128;             // 128N
    u16* h2b   = x2b + (size_t)N * 128;             // 16N
    u16* w2tb  = h2b + (size_t)N * 16;              // 2048
    u16* w1fh  = w2tb + 2048;                       // 16384
    u16* w1fl  = w1fh + 16384;                      // 16384
    float* as1 = (float*)(w1fl + 16384);            // 4N
    float* ad1 = as1 + (size_t)N * 4;               // 4N
    float* as2 = ad1 + (size_t)N * 4;               // N
    float* ad2 = as2 + N;                           // N
    float* u   = ad2 + N;                           // 128
    float* v   = u + 128;                           // 128
    float* wcsr  = v + 128;                         // 4E
    float* w2csr = wcsr + (size_t)E * 4;            // E
    int* deg    = (int*)(w2csr + E);                // N (+pad)
    int* rowptr = deg + ((N + 7) & ~3);             // N+1 (padded)
    int* bsum   = rowptr + ((N + 7) & ~3);          // 128
    int* colidx = bsum + 128;                       // E
    int* dstid  = colidx + E;                       // E
    int* rank   = dstid + E;                        // E

    const int NB  = (N + 1023) / 1024;              // 98
    const int Bh1 = (N + 63) / 64;
    const int Bhist = (E + 255) / 256;
    const int Bh2 = (N + 63) / 64;
    const int Bw2 = (E + 255) / 256;

    hipLaunchKernelGGL(ksetup, dim3(65 + NB), dim3(256), 0, stream,
                       W1, W2, ats2, atd2, w1fh, w1fl, u, v, w2tb, deg, N);
    hipLaunchKernelGGL(mega1, dim3(Bh1 + Bhist), dim3(256), 0, stream,
                       x, w1fh, w1fl, ats1, atd1, h1b, as1, ad1, N,
                       ei, deg, rank, E, Bh1);
    hipLaunchKernelGGL(kscan1, dim3(NB), dim3(256), 0, stream,
                       deg, rowptr, bsum, N);
    hipLaunchKernelGGL(kscan2, dim3(1), dim3(128), 0, stream, bsum, NB);
    hipLaunchKernelGGL(kscat, dim3((E + 255) / 256), dim3(256), 0, stream,
                       ei, rowptr, bsum, rank, as1, ad1, colidx, dstid, wcsr, E);
    hipLaunchKernelGGL(kg1, dim3((N + 3) / 4), dim3(256), 0, stream,
                       rowptr, bsum, colidx, wcsr, h1b, as1, ad1, b1, u, v,
                       x2b, as2, ad2, N, E);
    hipLaunchKernelGGL(mega2, dim3(Bh2 + Bw2), dim3(256), 0, stream,
                       x2b, w2tb, h2b, N, colidx, dstid, as2, ad2, w2csr, E, Bh2);
    hipLaunchKernelGGL(kg2, dim3((N + 3) / 4), dim3(256), 0, stream,
                       rowptr, bsum, colidx, w2csr, h2b, as2, ad2, b2, out, N, E);
}

// Round 8
// 358.871 us; speedup vs baseline: 1.2096x; 1.2096x over previous
//
#include <hip/hip_runtime.h>
#include <hip/hip_bf16.h>
#include <math.h>

// GAT 2-layer. Round 8: weights computed in-wave (phase A: 16 edges x 4 heads
// per instruction; phase B: broadcast via ds_bpermute/__shfl) — no wcsr/dstid
// side arrays, kscat back to single 4B scatter per edge. Launches: ksetup,
// mega1(kh1|khist), kscan1, kscan2, kscat, kg1, kh2, kg2.

typedef unsigned short u16;
typedef unsigned int u32;
typedef __attribute__((ext_vector_type(8))) short bf16x8;
typedef __attribute__((ext_vector_type(4))) float f32x4;

__device__ __forceinline__ float eluf(float v) { return v > 0.f ? v : expm1f(v); }
__device__ __forceinline__ u16 f2bf(float f) {
    u32 u = __float_as_uint(f);
    u += 0x7fff + ((u >> 16) & 1);          // RNE
    return (u16)(u >> 16);
}
__device__ __forceinline__ float bf2f(u16 u) {
    return __uint_as_float(((u32)u) << 16);
}
// exp(leaky02(e)) = exp2(e * (e>=0 ? log2e : 0.2*log2e))
__device__ __forceinline__ float expleaky(float e) {
    float m = e >= 0.f ? 1.44269504f : 0.28853901f;
    return exp2f(e * m);
}

// ---------------- ksetup: W1 frag swizzle | W2 prep | deg zero -------------
__global__ __launch_bounds__(256) void ksetup(
    const float* __restrict__ W1, const float* __restrict__ W2,
    const float* __restrict__ ats2, const float* __restrict__ atd2,
    u16* __restrict__ w1fh, u16* __restrict__ w1fl,
    float* __restrict__ u, float* __restrict__ v, u16* __restrict__ w2tb,
    int* __restrict__ deg, int N)
{
    const int b = blockIdx.x, tid = threadIdx.x;
    if (b < 64) {
        int idx = b * 256 + tid;
        int j = idx & 7, l = (idx >> 3) & 63, q = (idx >> 9) & 3, ct = idx >> 11;
        int k = q * 32 + (l >> 4) * 8 + j;
        int n = ct * 16 + (l & 15);
        float w = W1[k * 128 + n];
        u16 hv = f2bf(w);
        w1fh[idx] = hv;
        w1fl[idx] = f2bf(w - bf2f(hv));
    } else if (b == 64) {
        if (tid < 128) {
            float su = 0.f, sv = 0.f;
            #pragma unroll
            for (int j = 0; j < 16; ++j) {
                float w = W2[tid * 16 + j];
                su = fmaf(w, ats2[j], su);
                sv = fmaf(w, atd2[j], sv);
                w2tb[j * 128 + tid] = f2bf(w);
            }
            u[tid] = su; v[tid] = sv;
        }
    } else {
        int z = (b - 65) * 1024 + tid * 4;
        if (z < N) *(int4*)&deg[z] = make_int4(0, 0, 0, 0);
    }
}

// ---------------- mega1: kh1 (MFMA hi/lo GEMM) | khist ---------------------
__global__ __launch_bounds__(256) void mega1(
    const float* __restrict__ x, const u16* __restrict__ w1fh,
    const u16* __restrict__ w1fl,
    const float* __restrict__ att_s, const float* __restrict__ att_d,
    u16* __restrict__ h1b, float* __restrict__ as1, float* __restrict__ ad1,
    int N,
    const int* __restrict__ ei, int* __restrict__ deg, int* __restrict__ rank,
    int E, int Bh1)
{
    __shared__ u16 lh[8192];
    __shared__ u16 ll[8192];
    if (blockIdx.x >= Bh1) {               // khist role
        int e = (blockIdx.x - Bh1) * 256 + threadIdx.x;
        if (e < E) rank[e] = atomicAdd(&deg[ei[E + e]], 1);
        return;
    }
    const int tid = threadIdx.x;
    const int wv = tid >> 6, lane = tid & 63;
    const int base = blockIdx.x * 64 + wv * 16;
    const int m = lane & 15, quad = lane >> 4;

    int arow = base + m;
    if (arow >= N) arow = 0;
    const float* xr = &x[(size_t)arow * 128 + quad * 8];
    bf16x8 ah[4], al[4];
    #pragma unroll
    for (int q = 0; q < 4; ++q) {
        float4 f0 = *(const float4*)&xr[q * 32];
        float4 f1 = *(const float4*)&xr[q * 32 + 4];
        float fv[8] = {f0.x, f0.y, f0.z, f0.w, f1.x, f1.y, f1.z, f1.w};
        union { u16 us[8]; bf16x8 v; } hh, lu;
        #pragma unroll
        for (int j = 0; j < 8; ++j) {
            u16 h = f2bf(fv[j]);
            hh.us[j] = h;
            lu.us[j] = f2bf(fv[j] - bf2f(h));
        }
        ah[q] = hh.v; al[q] = lu.v;
    }

    for (int p = 0; p < 2; ++p) {
        __syncthreads();
        #pragma unroll
        for (int i = 0; i < 4; ++i) {
            int fi = (tid + i * 256) * 8;
            *(uint4*)&lh[fi] = *(const uint4*)&w1fh[p * 8192 + fi];
            *(uint4*)&ll[fi] = *(const uint4*)&w1fl[p * 8192 + fi];
        }
        __syncthreads();
        #pragma unroll
        for (int hh2 = 0; hh2 < 2; ++hh2) {
            const int h = p * 2 + hh2;
            float sp[4] = {0.f, 0.f, 0.f, 0.f};
            float dp[4] = {0.f, 0.f, 0.f, 0.f};
            #pragma unroll
            for (int sub = 0; sub < 2; ++sub) {
                const int ctl = hh2 * 2 + sub;
                const int ct = p * 4 + ctl;
                f32x4 acc = {0.f, 0.f, 0.f, 0.f};
                #pragma unroll
                for (int q = 0; q < 4; ++q) {
                    const int off = ((ctl * 4 + q) * 64 + lane) * 8;
                    bf16x8 bh = *(const bf16x8*)&lh[off];
                    bf16x8 bl = *(const bf16x8*)&ll[off];
                    acc = __builtin_amdgcn_mfma_f32_16x16x32_bf16(ah[q], bh, acc, 0, 0, 0);
                    acc = __builtin_amdgcn_mfma_f32_16x16x32_bf16(al[q], bh, acc, 0, 0, 0);
                    acc = __builtin_amdgcn_mfma_f32_16x16x32_bf16(ah[q], bl, acc, 0, 0, 0);
                }
                const float cs = att_s[h * 32 + sub * 16 + m];
                const float cd = att_d[h * 32 + sub * 16 + m];
                #pragma unroll
                for (int r = 0; r < 4; ++r) {
                    int rr = base + quad * 4 + r;
                    if (rr < N) h1b[(size_t)rr * 128 + ct * 16 + m] = f2bf(acc[r]);
                    sp[r] = fmaf(acc[r], cs, sp[r]);
                    dp[r] = fmaf(acc[r], cd, dp[r]);
                }
            }
            #pragma unroll
            for (int r = 0; r < 4; ++r) {
                sp[r] += __shfl_xor(sp[r], 1); sp[r] += __shfl_xor(sp[r], 2);
                sp[r] += __shfl_xor(sp[r], 4); sp[r] += __shfl_xor(sp[r], 8);
                dp[r] += __shfl_xor(dp[r], 1); dp[r] += __shfl_xor(dp[r], 2);
                dp[r] += __shfl_xor(dp[r], 4); dp[r] += __shfl_xor(dp[r], 8);
            }
            if (m == 0) {
                #pragma unroll
                for (int r = 0; r < 4; ++r) {
                    int rr = base + quad * 4 + r;
                    if (rr < N) {
                        as1[rr * 4 + h] = sp[r];
                        ad1[rr * 4 + h] = dp[r];
                    }
                }
            }
        }
    }
}

// ---------------- kscan1 / kscan2 ------------------------------------------
__global__ __launch_bounds__(256) void kscan1(
    const int* __restrict__ deg, int* __restrict__ rowptr,
    int* __restrict__ bsum, int N)
{
    __shared__ int lds[256];
    const int t = threadIdx.x;
    const int base = blockIdx.x * 1024 + t * 4;
    int v[4];
    int s = 0;
    #pragma unroll
    for (int j = 0; j < 4; ++j) {
        v[j] = (base + j < N) ? deg[base + j] : 0;
        s += v[j];
    }
    lds[t] = s;
    __syncthreads();
    for (int off = 1; off < 256; off <<= 1) {
        int y = (t >= off) ? lds[t - off] : 0;
        __syncthreads();
        lds[t] += y;
        __syncthreads();
    }
    int run = lds[t] - s;
    #pragma unroll
    for (int j = 0; j < 4; ++j) {
        if (base + j < N) rowptr[base + j] = run;
        run += v[j];
    }
    if (t == 255) bsum[blockIdx.x] = lds[255];
}

__global__ __launch_bounds__(128) void kscan2(int* __restrict__ bsum, int NB)
{
    __shared__ int lds[128];
    const int t = threadIdx.x;
    int v = (t < NB) ? bsum[t] : 0;
    lds[t] = v;
    __syncthreads();
    for (int off = 1; off < 128; off <<= 1) {
        int y = (t >= off) ? lds[t - off] : 0;
        __syncthreads();
        lds[t] += y;
        __syncthreads();
    }
    if (t < NB) bsum[t] = lds[t] - v;
}

// ---------------- kscat: colidx-only scatter -------------------------------
__global__ __launch_bounds__(256) void kscat(
    const int* __restrict__ ei, const int* __restrict__ rowptr,
    const int* __restrict__ bsum, const int* __restrict__ rank,
    int* __restrict__ colidx, int E)
{
    int e = blockIdx.x * 256 + threadIdx.x;
    if (e >= E) return;
    int s = ei[e], d = ei[E + e];
    colidx[rowptr[d] + bsum[d >> 10] + rank[e]] = s;
}

// ---------------- KG1: layer-1 gather, in-wave weights ---------------------
// Wave per node. Phase A: lane=(edge 0..15, head 0..3) computes 16 weights at
// once. Phase B: 8-batched gather, w via __shfl (ds_bpermute), exec full.
__global__ __launch_bounds__(256) void kg1(
    const int* __restrict__ rowptr, const int* __restrict__ bsum,
    const int* __restrict__ colidx,
    const u16* __restrict__ h1b, const float* __restrict__ as1,
    const float* __restrict__ ad1, const float* __restrict__ b1,
    const float* __restrict__ u, const float* __restrict__ v,
    u16* __restrict__ x2b, float* __restrict__ as2, float* __restrict__ ad2,
    int N, int E)
{
    const int d = blockIdx.x * 4 + (threadIdx.x >> 6);
    if (d >= N) return;
    const int lane = threadIdx.x & 63;
    const int c = lane * 2;
    const int headB = lane >> 4;     // phase-B head (channel group)
    const int headA = lane & 3;      // phase-A head
    const int eA = lane >> 2;        // phase-A edge slot 0..15

    const float adA = ad1[d * 4 + headA];
    const float wself = expleaky(as1[d * 4 + headB] + ad1[d * 4 + headB]);
    u32 hd = *(const u32*)&h1b[(d << 7) + c];
    float accx = wself * bf2f((u16)hd);
    float accy = wself * bf2f((u16)(hd >> 16));
    float den = wself;

    int i0r = rowptr[d] + bsum[d >> 10];
    int i1r = (d + 1 == N) ? E : rowptr[d + 1] + bsum[(d + 1) >> 10];
    const int i0 = __builtin_amdgcn_readfirstlane(i0r);
    const int i1 = __builtin_amdgcn_readfirstlane(i1r);

    for (int i = i0; i < i1; i += 16) {
        const int nb = min(16, i1 - i);
        // phase A: weights for up to 16 edges (masked lanes -> 0)
        const int ii = i + eA;
        const int iic = ii < i1 ? ii : i0;
        int sAv = colidx[iic];
        float wA = expleaky(as1[(sAv << 2) + headA] + adA);
        wA = (ii < i1) ? wA : 0.f;
        // phase B
        int e = 0;
        for (; e + 8 <= nb; e += 8) {
            int s0 = colidx[i + e + 0];
            int s1 = colidx[i + e + 1];
            int s2 = colidx[i + e + 2];
            int s3 = colidx[i + e + 3];
            int s4 = colidx[i + e + 4];
            int s5 = colidx[i + e + 5];
            int s6 = colidx[i + e + 6];
            int s7 = colidx[i + e + 7];
            float w0 = __shfl(wA, ((e + 0) << 2) + headB);
            float w1 = __shfl(wA, ((e + 1) << 2) + headB);
            float w2 = __shfl(wA, ((e + 2) << 2) + headB);
            float w3 = __shfl(wA, ((e + 3) << 2) + headB);
            float w4 = __shfl(wA, ((e + 4) << 2) + headB);
            float w5 = __shfl(wA, ((e + 5) << 2) + headB);
            float w6 = __shfl(wA, ((e + 6) << 2) + headB);
            float w7 = __shfl(wA, ((e + 7) << 2) + headB);
            u32 v0 = *(const u32*)&h1b[(s0 << 7) + c];
            u32 v1 = *(const u32*)&h1b[(s1 << 7) + c];
            u32 v2 = *(const u32*)&h1b[(s2 << 7) + c];
            u32 v3 = *(const u32*)&h1b[(s3 << 7) + c];
            u32 v4 = *(const u32*)&h1b[(s4 << 7) + c];
            u32 v5 = *(const u32*)&h1b[(s5 << 7) + c];
            u32 v6 = *(const u32*)&h1b[(s6 << 7) + c];
            u32 v7 = *(const u32*)&h1b[(s7 << 7) + c];
            accx = fmaf(w0, bf2f((u16)v0), accx); accy = fmaf(w0, bf2f((u16)(v0 >> 16)), accy);
            accx = fmaf(w1, bf2f((u16)v1), accx); accy = fmaf(w1, bf2f((u16)(v1 >> 16)), accy);
            accx = fmaf(w2, bf2f((u16)v2), accx); accy = fmaf(w2, bf2f((u16)(v2 >> 16)), accy);
            accx = fmaf(w3, bf2f((u16)v3), accx); accy = fmaf(w3, bf2f((u16)(v3 >> 16)), accy);
            accx = fmaf(w4, bf2f((u16)v4), accx); accy = fmaf(w4, bf2f((u16)(v4 >> 16)), accy);
            accx = fmaf(w5, bf2f((u16)v5), accx); accy = fmaf(w5, bf2f((u16)(v5 >> 16)), accy);
            accx = fmaf(w6, bf2f((u16)v6), accx); accy = fmaf(w6, bf2f((u16)(v6 >> 16)), accy);
            accx = fmaf(w7, bf2f((u16)v7), accx); accy = fmaf(w7, bf2f((u16)(v7 >> 16)), accy);
            den += ((w0 + w1) + (w2 + w3)) + ((w4 + w5) + (w6 + w7));
        }
        for (; e < nb; ++e) {
            int s = colidx[i + e];
            float w = __shfl(wA, (e << 2) + headB);
            u32 hv = *(const u32*)&h1b[(s << 7) + c];
            accx = fmaf(w, bf2f((u16)hv), accx);
            accy = fmaf(w, bf2f((u16)(hv >> 16)), accy);
            den += w;
        }
    }

    const float inv = 1.f / den;
    const float2 bv = *(const float2*)&b1[c];
    const float x2a = eluf(fmaf(accx, inv, bv.x));
    const float x2c = eluf(fmaf(accy, inv, bv.y));

    u32 pk = ((u32)f2bf(x2c) << 16) | (u32)f2bf(x2a);
    *(u32*)&x2b[(d << 7) + c] = pk;

    const float2 uv = *(const float2*)&u[c];
    const float2 vv = *(const float2*)&v[c];
    float sA = fmaf(x2a, uv.x, x2c * uv.y);
    float sB = fmaf(x2a, vv.x, x2c * vv.y);
    #pragma unroll
    for (int m = 1; m < 64; m <<= 1) {
        sA += __shfl_xor(sA, m);
        sB += __shfl_xor(sB, m);
    }
    if (lane == 0) { as2[d] = sA; ad2[d] = sB; }
}

// ---------------- KH2: h2 = x2 @ W2 via MFMA (bf16 out) --------------------
__global__ __launch_bounds__(256) void kh2(
    const u16* __restrict__ x2b, const u16* __restrict__ w2tb,
    u16* __restrict__ h2b, int N)
{
    const int wv = threadIdx.x >> 6, lane = threadIdx.x & 63;
    const int n0 = blockIdx.x * 64 + wv * 16;
    if (n0 >= N) return;
    const int m = lane & 15;
    const int kq = lane >> 4;
    bf16x8 bfr[4];
    #pragma unroll
    for (int q = 0; q < 4; ++q)
        bfr[q] = *(const bf16x8*)&w2tb[m * 128 + q * 32 + kq * 8];

    int ar = n0 + m;
    if (ar >= N) ar = N - 1;
    const u16* arow = &x2b[((size_t)ar << 7) + kq * 8];
    f32x4 acc = {0.f, 0.f, 0.f, 0.f};
    #pragma unroll
    for (int q = 0; q < 4; ++q) {
        bf16x8 af = *(const bf16x8*)&arow[q * 32];
        acc = __builtin_amdgcn_mfma_f32_16x16x32_bf16(af, bfr[q], acc, 0, 0, 0);
    }
    #pragma unroll
    for (int r = 0; r < 4; ++r) {
        int rr = n0 + kq * 4 + r;
        if (rr < N) h2b[((size_t)rr << 4) + m] = f2bf(acc[r]);
    }
}

// ---------------- KG2: layer-2 gather, in-wave weights ---------------------
// Wave per node. Phase A: 64 edges' weights at once (lane=edge). Phase B:
// 8 groups x 8 lanes x 2ch; w,s via __shfl, masked tail, exec full.
__global__ __launch_bounds__(256) void kg2(
    const int* __restrict__ rowptr, const int* __restrict__ bsum,
    const int* __restrict__ colidx,
    const u16* __restrict__ h2b, const float* __restrict__ as2,
    const float* __restrict__ ad2, const float* __restrict__ b2,
    float* __restrict__ out, int N, int E)
{
    const int d = blockIdx.x * 4 + (threadIdx.x >> 6);
    if (d >= N) return;
    const int lane = threadIdx.x & 63;
    const int ch = lane & 7, g = lane >> 3;

    const float ad_d = ad2[d];
    float acc0 = 0.f, acc1 = 0.f, den = 0.f;
    int i0r = rowptr[d] + bsum[d >> 10];
    int i1r = (d + 1 == N) ? E : rowptr[d + 1] + bsum[(d + 1) >> 10];
    const int i0 = __builtin_amdgcn_readfirstlane(i0r);
    const int i1 = __builtin_amdgcn_readfirstlane(i1r);

    for (int i = i0; i < i1; i += 64) {
        const int nb = min(64, i1 - i);
        const int idx = i + lane;
        const int idxc = idx < i1 ? idx : i0;
        int sA = colidx[idxc];
        float wA = expleaky(as2[sA] + ad_d);
        wA = (idx < i1) ? wA : 0.f;
        const int kU = (nb + 7) >> 3;
        for (int k = 0; k < kU; ++k) {
            int e = g + 8 * k;
            int ec = e < nb ? e : 0;
            float w = __shfl(wA, ec);
            int s = __shfl(sA, ec);
            if (e >= nb) w = 0.f;
            u32 hv = *(const u32*)&h2b[(s << 4) + ch * 2];
            acc0 = fmaf(w, bf2f((u16)hv), acc0);
            acc1 = fmaf(w, bf2f((u16)(hv >> 16)), acc1);
            den += w;
        }
    }
    acc0 += __shfl_xor(acc0, 8); acc0 += __shfl_xor(acc0, 16); acc0 += __shfl_xor(acc0, 32);
    acc1 += __shfl_xor(acc1, 8); acc1 += __shfl_xor(acc1, 16); acc1 += __shfl_xor(acc1, 32);
    den  += __shfl_xor(den, 8);  den  += __shfl_xor(den, 16);  den  += __shfl_xor(den, 32);

    const float wself = expleaky(as2[d] + ad_d);
    u32 hd = *(const u32*)&h2b[(d << 4) + ch * 2];
    acc0 = fmaf(wself, bf2f((u16)hd), acc0);
    acc1 = fmaf(wself, bf2f((u16)(hd >> 16)), acc1);
    den += wself;
    if (g == 0) {
        float2 ov = {acc0 / den + b2[ch * 2], acc1 / den + b2[ch * 2 + 1]};
        *(float2*)&out[(d << 4) + ch * 2] = ov;
    }
}

extern "C" void kernel_launch(void* const* d_in, const int* in_sizes, int n_in,
                              void* d_out, int out_size, void* d_ws, size_t ws_size,
                              hipStream_t stream) {
    const float* x    = (const float*)d_in[0];
    const int*   ei   = (const int*)d_in[1];
    const float* W1   = (const float*)d_in[2];
    const float* ats1 = (const float*)d_in[3];
    const float* atd1 = (const float*)d_in[4];
    const float* b1   = (const float*)d_in[5];
    const float* W2   = (const float*)d_in[6];
    const float* ats2 = (const float*)d_in[7];
    const float* atd2 = (const float*)d_in[8];
    const float* b2   = (const float*)d_in[9];
    float* out = (float*)d_out;
    const int N = in_sizes[0] / 128;
    const int E = in_sizes[1] / 2;

    u16* h1b   = (u16*)d_ws;                        // 128N
    u16* x2b   = h1b + (size_t)N * 128;             // 128N
    u16* h2b   = x2b + (size_t)N * 128;             // 16N
    u16* w2tb  = h2b + (size_t)N * 16;              // 2048
    u16* w1fh  = w2tb + 2048;                       // 16384
    u16* w1fl  = w1fh + 16384;                      // 16384
    float* as1 = (float*)(w1fl + 16384);            // 4N
    float* ad1 = as1 + (size_t)N * 4;               // 4N
    float* as2 = ad1 + (size_t)N * 4;               // N
    float* ad2 = as2 + N;                           // N
    float* u   = ad2 + N;                           // 128
    float* v   = u + 128;                           // 128
    int* deg    = (int*)(v + 128);                  // N (padded)
    int* rowptr = deg + ((N + 7) & ~3);             // N+1 (padded)
    int* bsum   = rowptr + ((N + 7) & ~3);          // 128
    int* colidx = bsum + 128;                       // E
    int* rank   = colidx + E;                       // E

    const int NB  = (N + 1023) / 1024;
    const int Bh1 = (N + 63) / 64;
    const int Bhist = (E + 255) / 256;

    hipLaunchKernelGGL(ksetup, dim3(65 + NB), dim3(256), 0, stream,
                       W1, W2, ats2, atd2, w1fh, w1fl, u, v, w2tb, deg, N);
    hipLaunchKernelGGL(mega1, dim3(Bh1 + Bhist), dim3(256), 0, stream,
                       x, w1fh, w1fl, ats1, atd1, h1b, as1, ad1, N,
                       ei, deg, rank, E, Bh1);
    hipLaunchKernelGGL(kscan1, dim3(NB), dim3(256), 0, stream,
                       deg, rowptr, bsum, N);
    hipLaunchKernelGGL(kscan2, dim3(1), dim3(128), 0, stream, bsum, NB);
    hipLaunchKernelGGL(kscat, dim3((E + 255) / 256), dim3(256), 0, stream,
                       ei, rowptr, bsum, rank, colidx, E);
    hipLaunchKernelGGL(kg1, dim3((N + 3) / 4), dim3(256), 0, stream,
                       rowptr, bsum, colidx, h1b, as1, ad1, b1, u, v,
                       x2b, as2, ad2, N, E);
    hipLaunchKernelGGL(kh2, dim3((N + 63) / 64), dim3(256), 0, stream,
                       x2b, w2tb, h2b, N);
    hipLaunchKernelGGL(kg2, dim3((N + 3) / 4), dim3(256), 0, stream,
                       rowptr, bsum, colidx, h2b, as2, ad2, b2, out, N, E);
}

// Round 9
// 340.539 us; speedup vs baseline: 1.2747x; 1.0538x over previous
//
#include <hip/hip_runtime.h>
#include <hip/hip_bf16.h>
#include <math.h>

// GAT 2-layer. Round 9: mega1 restructured — khist interleaved into the GEMM
// blocks (grid-stride prologue, atomic latency hidden under MFMA work; no
// separate khist blocks), and h1b written via LDS repack as full-line uint4
// stores (kills 2-byte scatter RMW). Everything else as R8.

typedef unsigned short u16;
typedef unsigned int u32;
typedef __attribute__((ext_vector_type(8))) short bf16x8;
typedef __attribute__((ext_vector_type(4))) float f32x4;

__device__ __forceinline__ float eluf(float v) { return v > 0.f ? v : expm1f(v); }
__device__ __forceinline__ u16 f2bf(float f) {
    u32 u = __float_as_uint(f);
    u += 0x7fff + ((u >> 16) & 1);          // RNE
    return (u16)(u >> 16);
}
__device__ __forceinline__ float bf2f(u16 u) {
    return __uint_as_float(((u32)u) << 16);
}
// exp(leaky02(e)) = exp2(e * (e>=0 ? log2e : 0.2*log2e))
__device__ __forceinline__ float expleaky(float e) {
    float m = e >= 0.f ? 1.44269504f : 0.28853901f;
    return exp2f(e * m);
}

// ---------------- ksetup: W1 frag swizzle | W2 prep | deg zero -------------
__global__ __launch_bounds__(256) void ksetup(
    const float* __restrict__ W1, const float* __restrict__ W2,
    const float* __restrict__ ats2, const float* __restrict__ atd2,
    u16* __restrict__ w1fh, u16* __restrict__ w1fl,
    float* __restrict__ u, float* __restrict__ v, u16* __restrict__ w2tb,
    int* __restrict__ deg, int N)
{
    const int b = blockIdx.x, tid = threadIdx.x;
    if (b < 64) {
        int idx = b * 256 + tid;
        int j = idx & 7, l = (idx >> 3) & 63, q = (idx >> 9) & 3, ct = idx >> 11;
        int k = q * 32 + (l >> 4) * 8 + j;
        int n = ct * 16 + (l & 15);
        float w = W1[k * 128 + n];
        u16 hv = f2bf(w);
        w1fh[idx] = hv;
        w1fl[idx] = f2bf(w - bf2f(hv));
    } else if (b == 64) {
        if (tid < 128) {
            float su = 0.f, sv = 0.f;
            #pragma unroll
            for (int j = 0; j < 16; ++j) {
                float w = W2[tid * 16 + j];
                su = fmaf(w, ats2[j], su);
                sv = fmaf(w, atd2[j], sv);
                w2tb[j * 128 + tid] = f2bf(w);
            }
            u[tid] = su; v[tid] = sv;
        }
    } else {
        int z = (b - 65) * 1024 + tid * 4;
        if (z < N) *(int4*)&deg[z] = make_int4(0, 0, 0, 0);
    }
}

// ---------------- mega1: khist prologue + MFMA hi/lo GEMM + repacked store -
#define REPSTRIDE 136   // u16 per row (272 B): 16B-aligned, 2-way bank alias
__global__ __launch_bounds__(256) void mega1(
    const float* __restrict__ x, const u16* __restrict__ w1fh,
    const u16* __restrict__ w1fl,
    const float* __restrict__ att_s, const float* __restrict__ att_d,
    u16* __restrict__ h1b, float* __restrict__ as1, float* __restrict__ ad1,
    int N,
    const int* __restrict__ ei, int* __restrict__ deg, int* __restrict__ rank,
    int E, int grid)
{
    __shared__ union {
        struct { u16 lh[8192]; u16 ll[8192]; } w;
        u16 rep[16384];
    } sm;
    const int tid = threadIdx.x;

    // --- khist, grid-strided: atomic latency hidden by the GEMM below ---
    for (int e = blockIdx.x * 256 + tid; e < E; e += grid * 256) {
        int dd = ei[E + e];
        rank[e] = atomicAdd(&deg[dd], 1);
    }

    const int wv = tid >> 6, lane = tid & 63;
    const int base = blockIdx.x * 64 + wv * 16;
    const int m = lane & 15, quad = lane >> 4;

    // A fragments (hi/lo split), row = base+m, k = q*32 + quad*8 + j
    int arow = base + m;
    if (arow >= N) arow = 0;
    const float* xr = &x[(size_t)arow * 128 + quad * 8];
    bf16x8 ah[4], al[4];
    #pragma unroll
    for (int q = 0; q < 4; ++q) {
        float4 f0 = *(const float4*)&xr[q * 32];
        float4 f1 = *(const float4*)&xr[q * 32 + 4];
        float fv[8] = {f0.x, f0.y, f0.z, f0.w, f1.x, f1.y, f1.z, f1.w};
        union { u16 us[8]; bf16x8 v; } hh, lu;
        #pragma unroll
        for (int j = 0; j < 8; ++j) {
            u16 h = f2bf(fv[j]);
            hh.us[j] = h;
            lu.us[j] = f2bf(fv[j] - bf2f(h));
        }
        ah[q] = hh.v; al[q] = lu.v;
    }

    f32x4 accs[8];
    for (int p = 0; p < 2; ++p) {
        __syncthreads();
        #pragma unroll
        for (int i = 0; i < 4; ++i) {
            int fi = (tid + i * 256) * 8;
            *(uint4*)&sm.w.lh[fi] = *(const uint4*)&w1fh[p * 8192 + fi];
            *(uint4*)&sm.w.ll[fi] = *(const uint4*)&w1fl[p * 8192 + fi];
        }
        __syncthreads();
        #pragma unroll
        for (int ctl = 0; ctl < 4; ++ctl) {
            f32x4 acc = {0.f, 0.f, 0.f, 0.f};
            #pragma unroll
            for (int q = 0; q < 4; ++q) {
                const int off = ((ctl * 4 + q) * 64 + lane) * 8;
                bf16x8 bh = *(const bf16x8*)&sm.w.lh[off];
                bf16x8 bl = *(const bf16x8*)&sm.w.ll[off];
                acc = __builtin_amdgcn_mfma_f32_16x16x32_bf16(ah[q], bh, acc, 0, 0, 0);
                acc = __builtin_amdgcn_mfma_f32_16x16x32_bf16(al[q], bh, acc, 0, 0, 0);
                acc = __builtin_amdgcn_mfma_f32_16x16x32_bf16(ah[q], bl, acc, 0, 0, 0);
            }
            accs[p * 4 + ctl] = acc;
        }
    }

    // attention dots: head h covers cts {2h, 2h+1}; col = h*32 + sub*16 + m
    #pragma unroll
    for (int h = 0; h < 4; ++h) {
        const float cs0 = att_s[h * 32 + m];
        const float cs1 = att_s[h * 32 + 16 + m];
        const float cd0 = att_d[h * 32 + m];
        const float cd1 = att_d[h * 32 + 16 + m];
        float sp[4], dp[4];
        #pragma unroll
        for (int r = 0; r < 4; ++r) {
            sp[r] = fmaf(accs[2 * h][r], cs0, accs[2 * h + 1][r] * cs1);
            dp[r] = fmaf(accs[2 * h][r], cd0, accs[2 * h + 1][r] * cd1);
        }
        #pragma unroll
        for (int r = 0; r < 4; ++r) {
            sp[r] += __shfl_xor(sp[r], 1); sp[r] += __shfl_xor(sp[r], 2);
            sp[r] += __shfl_xor(sp[r], 4); sp[r] += __shfl_xor(sp[r], 8);
            dp[r] += __shfl_xor(dp[r], 1); dp[r] += __shfl_xor(dp[r], 2);
            dp[r] += __shfl_xor(dp[r], 4); dp[r] += __shfl_xor(dp[r], 8);
        }
        if (m == 0) {
            #pragma unroll
            for (int r = 0; r < 4; ++r) {
                int rr = base + quad * 4 + r;
                if (rr < N) {
                    as1[rr * 4 + h] = sp[r];
                    ad1[rr * 4 + h] = dp[r];
                }
            }
        }
    }

    // repack -> coalesced full-line h1b stores
    __syncthreads();                         // everyone done with lh/ll
    u16* rep = sm.rep + wv * (16 * REPSTRIDE);
    #pragma unroll
    for (int ct = 0; ct < 8; ++ct) {
        #pragma unroll
        for (int r = 0; r < 4; ++r)
            rep[(quad * 4 + r) * REPSTRIDE + ct * 16 + m] = f2bf(accs[ct][r]);
    }
    const int rr0 = lane >> 2, cc = lane & 3;
    #pragma unroll
    for (int round = 0; round < 4; ++round) {
        int chunk = cc + 4 * round;          // 16B chunk within 256B row
        uint4 vv = *(const uint4*)&rep[rr0 * REPSTRIDE + chunk * 8];
        int grow = base + rr0;
        if (grow < N)
            *(uint4*)&h1b[(size_t)grow * 128 + chunk * 8] = vv;
    }
}

// ---------------- kscan1 / kscan2 ------------------------------------------
__global__ __launch_bounds__(256) void kscan1(
    const int* __restrict__ deg, int* __restrict__ rowptr,
    int* __restrict__ bsum, int N)
{
    __shared__ int lds[256];
    const int t = threadIdx.x;
    const int base = blockIdx.x * 1024 + t * 4;
    int v[4];
    int s = 0;
    #pragma unroll
    for (int j = 0; j < 4; ++j) {
        v[j] = (base + j < N) ? deg[base + j] : 0;
        s += v[j];
    }
    lds[t] = s;
    __syncthreads();
    for (int off = 1; off < 256; off <<= 1) {
        int y = (t >= off) ? lds[t - off] : 0;
        __syncthreads();
        lds[t] += y;
        __syncthreads();
    }
    int run = lds[t] - s;
    #pragma unroll
    for (int j = 0; j < 4; ++j) {
        if (base + j < N) rowptr[base + j] = run;
        run += v[j];
    }
    if (t == 255) bsum[blockIdx.x] = lds[255];
}

__global__ __launch_bounds__(128) void kscan2(int* __restrict__ bsum, int NB)
{
    __shared__ int lds[128];
    const int t = threadIdx.x;
    int v = (t < NB) ? bsum[t] : 0;
    lds[t] = v;
    __syncthreads();
    for (int off = 1; off < 128; off <<= 1) {
        int y = (t >= off) ? lds[t - off] : 0;
        __syncthreads();
        lds[t] += y;
        __syncthreads();
    }
    if (t < NB) bsum[t] = lds[t] - v;
}

// ---------------- kscat: colidx-only scatter -------------------------------
__global__ __launch_bounds__(256) void kscat(
    const int* __restrict__ ei, const int* __restrict__ rowptr,
    const int* __restrict__ bsum, const int* __restrict__ rank,
    int* __restrict__ colidx, int E)
{
    int e = blockIdx.x * 256 + threadIdx.x;
    if (e >= E) return;
    int s = ei[e], d = ei[E + e];
    colidx[rowptr[d] + bsum[d >> 10] + rank[e]] = s;
}

// ---------------- KG1: layer-1 gather, in-wave weights ---------------------
__global__ __launch_bounds__(256) void kg1(
    const int* __restrict__ rowptr, const int* __restrict__ bsum,
    const int* __restrict__ colidx,
    const u16* __restrict__ h1b, const float* __restrict__ as1,
    const float* __restrict__ ad1, const float* __restrict__ b1,
    const float* __restrict__ u, const float* __restrict__ v,
    u16* __restrict__ x2b, float* __restrict__ as2, float* __restrict__ ad2,
    int N, int E)
{
    const int d = blockIdx.x * 4 + (threadIdx.x >> 6);
    if (d >= N) return;
    const int lane = threadIdx.x & 63;
    const int c = lane * 2;
    const int headB = lane >> 4;
    const int headA = lane & 3;
    const int eA = lane >> 2;

    const float adA = ad1[d * 4 + headA];
    const float wself = expleaky(as1[d * 4 + headB] + ad1[d * 4 + headB]);
    u32 hd = *(const u32*)&h1b[(d << 7) + c];
    float accx = wself * bf2f((u16)hd);
    float accy = wself * bf2f((u16)(hd >> 16));
    float den = wself;

    int i0r = rowptr[d] + bsum[d >> 10];
    int i1r = (d + 1 == N) ? E : rowptr[d + 1] + bsum[(d + 1) >> 10];
    const int i0 = __builtin_amdgcn_readfirstlane(i0r);
    const int i1 = __builtin_amdgcn_readfirstlane(i1r);

    for (int i = i0; i < i1; i += 16) {
        const int nb = min(16, i1 - i);
        const int ii = i + eA;
        const int iic = ii < i1 ? ii : i0;
        int sAv = colidx[iic];
        float wA = expleaky(as1[(sAv << 2) + headA] + adA);
        wA = (ii < i1) ? wA : 0.f;
        int e = 0;
        for (; e + 8 <= nb; e += 8) {
            int s0 = colidx[i + e + 0];
            int s1 = colidx[i + e + 1];
            int s2 = colidx[i + e + 2];
            int s3 = colidx[i + e + 3];
            int s4 = colidx[i + e + 4];
            int s5 = colidx[i + e + 5];
            int s6 = colidx[i + e + 6];
            int s7 = colidx[i + e + 7];
            float w0 = __shfl(wA, ((e + 0) << 2) + headB);
            float w1 = __shfl(wA, ((e + 1) << 2) + headB);
            float w2 = __shfl(wA, ((e + 2) << 2) + headB);
            float w3 = __shfl(wA, ((e + 3) << 2) + headB);
            float w4 = __shfl(wA, ((e + 4) << 2) + headB);
            float w5 = __shfl(wA, ((e + 5) << 2) + headB);
            float w6 = __shfl(wA, ((e + 6) << 2) + headB);
            float w7 = __shfl(wA, ((e + 7) << 2) + headB);
            u32 v0 = *(const u32*)&h1b[(s0 << 7) + c];
            u32 v1 = *(const u32*)&h1b[(s1 << 7) + c];
            u32 v2 = *(const u32*)&h1b[(s2 << 7) + c];
            u32 v3 = *(const u32*)&h1b[(s3 << 7) + c];
            u32 v4 = *(const u32*)&h1b[(s4 << 7) + c];
            u32 v5 = *(const u32*)&h1b[(s5 << 7) + c];
            u32 v6 = *(const u32*)&h1b[(s6 << 7) + c];
            u32 v7 = *(const u32*)&h1b[(s7 << 7) + c];
            accx = fmaf(w0, bf2f((u16)v0), accx); accy = fmaf(w0, bf2f((u16)(v0 >> 16)), accy);
            accx = fmaf(w1, bf2f((u16)v1), accx); accy = fmaf(w1, bf2f((u16)(v1 >> 16)), accy);
            accx = fmaf(w2, bf2f((u16)v2), accx); accy = fmaf(w2, bf2f((u16)(v2 >> 16)), accy);
            accx = fmaf(w3, bf2f((u16)v3), accx); accy = fmaf(w3, bf2f((u16)(v3 >> 16)), accy);
            accx = fmaf(w4, bf2f((u16)v4), accx); accy = fmaf(w4, bf2f((u16)(v4 >> 16)), accy);
            accx = fmaf(w5, bf2f((u16)v5), accx); accy = fmaf(w5, bf2f((u16)(v5 >> 16)), accy);
            accx = fmaf(w6, bf2f((u16)v6), accx); accy = fmaf(w6, bf2f((u16)(v6 >> 16)), accy);
            accx = fmaf(w7, bf2f((u16)v7), accx); accy = fmaf(w7, bf2f((u16)(v7 >> 16)), accy);
            den += ((w0 + w1) + (w2 + w3)) + ((w4 + w5) + (w6 + w7));
        }
        for (; e < nb; ++e) {
            int s = colidx[i + e];
            float w = __shfl(wA, (e << 2) + headB);
            u32 hv = *(const u32*)&h1b[(s << 7) + c];
            accx = fmaf(w, bf2f((u16)hv), accx);
            accy = fmaf(w, bf2f((u16)(hv >> 16)), accy);
            den += w;
        }
    }

    const float inv = 1.f / den;
    const float2 bv = *(const float2*)&b1[c];
    const float x2a = eluf(fmaf(accx, inv, bv.x));
    const float x2c = eluf(fmaf(accy, inv, bv.y));

    u32 pk = ((u32)f2bf(x2c) << 16) | (u32)f2bf(x2a);
    *(u32*)&x2b[(d << 7) + c] = pk;

    const float2 uv = *(const float2*)&u[c];
    const float2 vv = *(const float2*)&v[c];
    float sA = fmaf(x2a, uv.x, x2c * uv.y);
    float sB = fmaf(x2a, vv.x, x2c * vv.y);
    #pragma unroll
    for (int m = 1; m < 64; m <<= 1) {
        sA += __shfl_xor(sA, m);
        sB += __shfl_xor(sB, m);
    }
    if (lane == 0) { as2[d] = sA; ad2[d] = sB; }
}

// ---------------- KH2: h2 = x2 @ W2 via MFMA (bf16 out) --------------------
__global__ __launch_bounds__(256) void kh2(
    const u16* __restrict__ x2b, const u16* __restrict__ w2tb,
    u16* __restrict__ h2b, int N)
{
    const int wv = threadIdx.x >> 6, lane = threadIdx.x & 63;
    const int n0 = blockIdx.x * 64 + wv * 16;
    if (n0 >= N) return;
    const int m = lane & 15;
    const int kq = lane >> 4;
    bf16x8 bfr[4];
    #pragma unroll
    for (int q = 0; q < 4; ++q)
        bfr[q] = *(const bf16x8*)&w2tb[m * 128 + q * 32 + kq * 8];

    int ar = n0 + m;
    if (ar >= N) ar = N - 1;
    const u16* arow = &x2b[((size_t)ar << 7) + kq * 8];
    f32x4 acc = {0.f, 0.f, 0.f, 0.f};
    #pragma unroll
    for (int q = 0; q < 4; ++q) {
        bf16x8 af = *(const bf16x8*)&arow[q * 32];
        acc = __builtin_amdgcn_mfma_f32_16x16x32_bf16(af, bfr[q], acc, 0, 0, 0);
    }
    #pragma unroll
    for (int r = 0; r < 4; ++r) {
        int rr = n0 + kq * 4 + r;
        if (rr < N) h2b[((size_t)rr << 4) + m] = f2bf(acc[r]);
    }
}

// ---------------- KG2: layer-2 gather, in-wave weights ---------------------
__global__ __launch_bounds__(256) void kg2(
    const int* __restrict__ rowptr, const int* __restrict__ bsum,
    const int* __restrict__ colidx,
    const u16* __restrict__ h2b, const float* __restrict__ as2,
    const float* __restrict__ ad2, const float* __restrict__ b2,
    float* __restrict__ out, int N, int E)
{
    const int d = blockIdx.x * 4 + (threadIdx.x >> 6);
    if (d >= N) return;
    const int lane = threadIdx.x & 63;
    const int ch = lane & 7, g = lane >> 3;

    const float ad_d = ad2[d];
    float acc0 = 0.f, acc1 = 0.f, den = 0.f;
    int i0r = rowptr[d] + bsum[d >> 10];
    int i1r = (d + 1 == N) ? E : rowptr[d + 1] + bsum[(d + 1) >> 10];
    const int i0 = __builtin_amdgcn_readfirstlane(i0r);
    const int i1 = __builtin_amdgcn_readfirstlane(i1r);

    for (int i = i0; i < i1; i += 64) {
        const int nb = min(64, i1 - i);
        const int idx = i + lane;
        const int idxc = idx < i1 ? idx : i0;
        int sA = colidx[idxc];
        float wA = expleaky(as2[sA] + ad_d);
        wA = (idx < i1) ? wA : 0.f;
        const int kU = (nb + 7) >> 3;
        for (int k = 0; k < kU; ++k) {
            int e = g + 8 * k;
            int ec = e < nb ? e : 0;
            float w = __shfl(wA, ec);
            int s = __shfl(sA, ec);
            if (e >= nb) w = 0.f;
            u32 hv = *(const u32*)&h2b[(s << 4) + ch * 2];
            acc0 = fmaf(w, bf2f((u16)hv), acc0);
            acc1 = fmaf(w, bf2f((u16)(hv >> 16)), acc1);
            den += w;
        }
    }
    acc0 += __shfl_xor(acc0, 8); acc0 += __shfl_xor(acc0, 16); acc0 += __shfl_xor(acc0, 32);
    acc1 += __shfl_xor(acc1, 8); acc1 += __shfl_xor(acc1, 16); acc1 += __shfl_xor(acc1, 32);
    den  += __shfl_xor(den, 8);  den  += __shfl_xor(den, 16);  den  += __shfl_xor(den, 32);

    const float wself = expleaky(as2[d] + ad_d);
    u32 hd = *(const u32*)&h2b[(d << 4) + ch * 2];
    acc0 = fmaf(wself, bf2f((u16)hd), acc0);
    acc1 = fmaf(wself, bf2f((u16)(hd >> 16)), acc1);
    den += wself;
    if (g == 0) {
        float2 ov = {acc0 / den + b2[ch * 2], acc1 / den + b2[ch * 2 + 1]};
        *(float2*)&out[(d << 4) + ch * 2] = ov;
    }
}

extern "C" void kernel_launch(void* const* d_in, const int* in_sizes, int n_in,
                              void* d_out, int out_size, void* d_ws, size_t ws_size,
                              hipStream_t stream) {
    const float* x    = (const float*)d_in[0];
    const int*   ei   = (const int*)d_in[1];
    const float* W1   = (const float*)d_in[2];
    const float* ats1 = (const float*)d_in[3];
    const float* atd1 = (const float*)d_in[4];
    const float* b1   = (const float*)d_in[5];
    const float* W2   = (const float*)d_in[6];
    const float* ats2 = (const float*)d_in[7];
    const float* atd2 = (const float*)d_in[8];
    const float* b2   = (const float*)d_in[9];
    float* out = (float*)d_out;
    const int N = in_sizes[0] / 128;
    const int E = in_sizes[1] / 2;

    u16* h1b   = (u16*)d_ws;                        // 128N
    u16* x2b   = h1b + (size_t)N * 128;             // 128N
    u16* h2b   = x2b + (size_t)N * 128;             // 16N
    u16* w2tb  = h2b + (size_t)N * 16;              // 2048
    u16* w1fh  = w2tb + 2048;                       // 16384
    u16* w1fl  = w1fh + 16384;                      // 16384
    float* as1 = (float*)(w1fl + 16384);            // 4N
    float* ad1 = as1 + (size_t)N * 4;               // 4N
    float* as2 = ad1 + (size_t)N * 4;               // N
    float* ad2 = as2 + N;                           // N
    float* u   = ad2 + N;                           // 128
    float* v   = u + 128;                           // 128
    int* deg    = (int*)(v + 128);                  // N (padded)
    int* rowptr = deg + ((N + 7) & ~3);             // N+1 (padded)
    int* bsum   = rowptr + ((N + 7) & ~3);          // 128
    int* colidx = bsum + 128;                       // E
    int* rank   = colidx + E;                       // E

    const int NB  = (N + 1023) / 1024;
    const int Bh1 = (N + 63) / 64;

    hipLaunchKernelGGL(ksetup, dim3(65 + NB), dim3(256), 0, stream,
                       W1, W2, ats2, atd2, w1fh, w1fl, u, v, w2tb, deg, N);
    hipLaunchKernelGGL(mega1, dim3(Bh1), dim3(256), 0, stream,
                       x, w1fh, w1fl, ats1, atd1, h1b, as1, ad1, N,
                       ei, deg, rank, E, Bh1);
    hipLaunchKernelGGL(kscan1, dim3(NB), dim3(256), 0, stream,
                       deg, rowptr, bsum, N);
    hipLaunchKernelGGL(kscan2, dim3(1), dim3(128), 0, stream, bsum, NB);
    hipLaunchKernelGGL(kscat, dim3((E + 255) / 256), dim3(256), 0, stream,
                       ei, rowptr, bsum, rank, colidx, E);
    hipLaunchKernelGGL(kg1, dim3((N + 3) / 4), dim3(256), 0, stream,
                       rowptr, bsum, colidx, h1b, as1, ad1, b1, u, v,
                       x2b, as2, ad2, N, E);
    hipLaunchKernelGGL(kh2, dim3((N + 63) / 64), dim3(256), 0, stream,
                       x2b, w2tb, h2b, N);
    hipLaunchKernelGGL(kg2, dim3((N + 3) / 4), dim3(256), 0, stream,
                       rowptr, bsum, colidx, h2b, as2, ad2, b2, out, N, E);
}